// Round 1
// baseline (2176.833 us; speedup 1.0000x reference)
//
#include <hip/hip_runtime.h>
#include <hip/hip_bf16.h>

// LightGCN forward on MI355X.
// Node order: users [0,U), items [U, U+I). D = 128 fixed.
// out = (x0 + A x0 + A A x0) / 3, A = D^-1/2 (Adj) D^-1/2, no self loops.

#define DIM 128

__global__ void deg_kernel(const int* __restrict__ ui_dst,
                           const int* __restrict__ iu_dst,
                           int E, int U, int* __restrict__ deg) {
    int e = blockIdx.x * blockDim.x + threadIdx.x;
    if (e < E) {
        // dst of first half edges: item node (offset U); second half: user node.
        atomicAdd(&deg[ui_dst[e] + U], 1);
        atomicAdd(&deg[iu_dst[e]], 1);
    }
}

__global__ void dinv_kernel(const int* __restrict__ deg,
                            float* __restrict__ dinv, int N) {
    int n = blockIdx.x * blockDim.x + threadIdx.x;
    if (n < N) {
        int d = deg[n];
        dinv[n] = (d > 0) ? (1.0f / sqrtf((float)d)) : 0.0f;
    }
}

// Edge-parallel scatter: out[dst] += x[src] * dinv[src]*dinv[dst] * scale.
// 32 threads per directed edge, 4 floats (one float4) per thread.
// Source x is addressed split: node n < U -> xu + n*D, else xi + (n-U)*D.
// (For a contiguous source buffer T, pass xu=T, xi=T+U*D — same addressing.)
__global__ void edge_scatter(const float* __restrict__ xu,
                             const float* __restrict__ xi,
                             const int* __restrict__ ui_src,
                             const int* __restrict__ ui_dst,
                             const int* __restrict__ iu_src,
                             const int* __restrict__ iu_dst,
                             const float* __restrict__ dinv,
                             int E, int U, float scale,
                             float* __restrict__ out) {
    long idx = (long)blockIdx.x * blockDim.x + threadIdx.x;
    int lane = (int)(idx & 31);
    long e = idx >> 5;
    long E2 = 2L * E;
    if (e >= E2) return;

    int s, d;
    if (e < E) {
        s = ui_src[e];
        d = ui_dst[e] + U;
    } else {
        long k = e - E;
        s = iu_src[k] + U;
        d = iu_dst[k];
    }
    float w = dinv[s] * dinv[d] * scale;

    const float* xs = (s < U) ? (xu + (size_t)s * DIM)
                              : (xi + (size_t)(s - U) * DIM);
    float4 v = *reinterpret_cast<const float4*>(xs + lane * 4);
    float* od = out + (size_t)d * DIM + lane * 4;
    atomicAdd(od + 0, v.x * w);
    atomicAdd(od + 1, v.y * w);
    atomicAdd(od + 2, v.z * w);
    atomicAdd(od + 3, v.w * w);
}

// out = (x0 + T) * (1/3), element-wise over all N*D floats (float4-vectorized).
__global__ void combine_kernel(const float* __restrict__ xu,
                               const float* __restrict__ xi,
                               const float* __restrict__ T,
                               long uelems, long total,
                               float* __restrict__ out) {
    long i4 = ((long)blockIdx.x * blockDim.x + threadIdx.x) * 4;
    if (i4 >= total) return;
    float4 t = *reinterpret_cast<const float4*>(T + i4);
    const float* x0p = (i4 < uelems) ? (xu + i4) : (xi + (i4 - uelems));
    float4 v = *reinterpret_cast<const float4*>(x0p);
    const float k = 1.0f / 3.0f;
    float4 r;
    r.x = (v.x + t.x) * k;
    r.y = (v.y + t.y) * k;
    r.z = (v.z + t.z) * k;
    r.w = (v.w + t.w) * k;
    *reinterpret_cast<float4*>(out + i4) = r;
}

extern "C" void kernel_launch(void* const* d_in, const int* in_sizes, int n_in,
                              void* d_out, int out_size, void* d_ws, size_t ws_size,
                              hipStream_t stream) {
    const float* user_emb = (const float*)d_in[0];
    const float* item_emb = (const float*)d_in[1];
    const int* ui_src = (const int*)d_in[2];
    const int* ui_dst = (const int*)d_in[3];
    const int* iu_src = (const int*)d_in[4];
    const int* iu_dst = (const int*)d_in[5];

    const int E = in_sizes[2];
    const int U = in_sizes[0] / DIM;
    const int I = in_sizes[1] / DIM;
    const int N = U + I;
    const long uelems = (long)U * DIM;
    const long total = (long)N * DIM;

    float* out = (float*)d_out;

    // ws layout: deg (N int), dinv (N float), T (N*D float)
    int* deg = (int*)d_ws;
    float* dinv = (float*)((char*)d_ws + (size_t)N * 4);
    float* T = (float*)((char*)d_ws + (size_t)2 * N * 4);  // 1.2MB offset, 16B aligned

    hipMemsetAsync(deg, 0, (size_t)N * 4, stream);
    hipMemsetAsync(T, 0, (size_t)total * 4, stream);

    // degrees + normalization
    deg_kernel<<<(E + 255) / 256, 256, 0, stream>>>(ui_dst, iu_dst, E, U, deg);
    dinv_kernel<<<(N + 255) / 256, 256, 0, stream>>>(deg, dinv, N);

    // layer 1: T = A x0
    {
        long threads = 2L * E * 32;
        int blocks = (int)((threads + 255) / 256);
        edge_scatter<<<blocks, 256, 0, stream>>>(user_emb, item_emb,
                                                 ui_src, ui_dst, iu_src, iu_dst,
                                                 dinv, E, U, 1.0f, T);
    }

    // out = (x0 + T) / 3
    {
        long blocks = (total / 4 + 255) / 256;
        combine_kernel<<<(int)blocks, 256, 0, stream>>>(user_emb, item_emb, T,
                                                        uelems, total, out);
    }

    // layer 2 folded: out += (A T) / 3
    {
        long threads = 2L * E * 32;
        int blocks = (int)((threads + 255) / 256);
        edge_scatter<<<blocks, 256, 0, stream>>>(T, T + uelems,
                                                 ui_src, ui_dst, iu_src, iu_dst,
                                                 dinv, E, U, 1.0f / 3.0f, out);
    }
}

// Round 2
// 390.217 us; speedup vs baseline: 5.5785x; 5.5785x over previous
//
#include <hip/hip_runtime.h>
#include <hip/hip_bf16.h>

// LightGCN forward on MI355X — pull-based (CSR gather), no output atomics.
// Node order: users [0,U), items [U, U+I). D = 128 fixed.
// out = (x0 + A x0 + A A x0) / 3, A = D^-1/2 Adj D^-1/2 (no self loops).

#define DIM 128

// ---------------- degree histogram ----------------
__global__ void deg_kernel(const int* __restrict__ ui_dst,
                           const int* __restrict__ iu_dst,
                           int E, int U, int* __restrict__ deg) {
    int e = blockIdx.x * blockDim.x + threadIdx.x;
    if (e < E) {
        atomicAdd(&deg[ui_dst[e] + U], 1);
        atomicAdd(&deg[iu_dst[e]], 1);
    }
}

// ---------------- hierarchical exclusive scan ----------------
// Block-level inclusive scan for blocks up to 1024 threads (<=16 waves).
__device__ __forceinline__ int block_incl_scan(int v, int* lds) {
    int lane = threadIdx.x & 63;
    int wid = threadIdx.x >> 6;
    int nw = (blockDim.x + 63) >> 6;
    // wave inclusive scan
    #pragma unroll
    for (int off = 1; off < 64; off <<= 1) {
        int t = __shfl_up(v, off);
        if (lane >= off) v += t;
    }
    if (lane == 63) lds[wid] = v;
    __syncthreads();
    if (threadIdx.x == 0) {
        int s = 0;
        for (int w = 0; w < nw; w++) { int t = lds[w]; lds[w] = s; s += t; }
    }
    __syncthreads();
    return v + lds[wid];
}

// pass 1: per-block (256 elems) sums
__global__ void scan_partial_kernel(const int* __restrict__ deg, int N,
                                    int* __restrict__ partials) {
    __shared__ int lds[16];
    int i = blockIdx.x * 256 + threadIdx.x;
    int v = (i < N) ? deg[i] : 0;
    int incl = block_incl_scan(v, lds);
    if (threadIdx.x == 255) partials[blockIdx.x] = incl;
}

// pass 2: single block scans partials (P <= 1024), writes row_ptr[N] = total
__global__ void scan_top_kernel(int* __restrict__ partials, int P,
                                int* __restrict__ row_ptr, int N) {
    __shared__ int lds[16];
    int i = threadIdx.x;
    int v = (i < P) ? partials[i] : 0;
    int incl = block_incl_scan(v, lds);
    if (i < P) partials[i] = incl - v;           // exclusive
    if (i == (int)blockDim.x - 1) row_ptr[N] = incl;  // grand total
}

// pass 3: final exclusive scan + cursor copy + dinv
__global__ void scan_final_kernel(const int* __restrict__ deg, int N,
                                  const int* __restrict__ partials,
                                  int* __restrict__ row_ptr,
                                  int* __restrict__ cursor,
                                  float* __restrict__ dinv) {
    __shared__ int lds[16];
    int i = blockIdx.x * 256 + threadIdx.x;
    int v = (i < N) ? deg[i] : 0;
    int incl = block_incl_scan(v, lds);
    if (i < N) {
        int excl = incl - v + partials[blockIdx.x];
        row_ptr[i] = excl;
        cursor[i] = excl;
        dinv[i] = (v > 0) ? (1.0f / sqrtf((float)v)) : 0.0f;
    }
}

// ---------------- CSR fill (by destination) ----------------
__global__ void fill_kernel(const int* __restrict__ ui_src,
                            const int* __restrict__ ui_dst,
                            const int* __restrict__ iu_src,
                            const int* __restrict__ iu_dst,
                            int E, int U,
                            int* __restrict__ cursor, int* __restrict__ adj) {
    int e = blockIdx.x * blockDim.x + threadIdx.x;
    if (e >= E) return;
    int s = ui_src[e], d = ui_dst[e] + U;
    int pos = atomicAdd(&cursor[d], 1);
    adj[pos] = s;
    s = iu_src[e] + U; d = iu_dst[e];
    pos = atomicAdd(&cursor[d], 1);
    adj[pos] = s;
}

// ---------------- gather layer 1: T[d] = dinv[d] * sum_s x0[s]*dinv[s] ----------------
// one wave (64 lanes) per dst node, float2 per lane (D=128).
__global__ void gather1_kernel(const float* __restrict__ xu,
                               const float* __restrict__ xi,
                               const int* __restrict__ row_ptr,
                               const int* __restrict__ adj,
                               const float* __restrict__ dinv,
                               int N, int U, float* __restrict__ T) {
    long gt = (long)blockIdx.x * blockDim.x + threadIdx.x;
    int lane = (int)(gt & 63);
    long node = gt >> 6;
    if (node >= N) return;
    int start = row_ptr[node], end = row_ptr[node + 1];
    float2 acc = {0.f, 0.f};
    for (int j = start; j < end; j++) {
        int s = adj[j];
        float w = dinv[s];
        const float* xs = (s < U) ? (xu + (size_t)s * DIM)
                                  : (xi + (size_t)(s - U) * DIM);
        float2 v = *reinterpret_cast<const float2*>(xs + lane * 2);
        acc.x += v.x * w;
        acc.y += v.y * w;
    }
    float dd = dinv[node];
    float2 r = {acc.x * dd, acc.y * dd};
    *reinterpret_cast<float2*>(T + (size_t)node * DIM + lane * 2) = r;
}

// ---------------- gather layer 2 fused with combine ----------------
// out[d] = (x0[d] + T[d] + dinv[d]*sum_s T[s]*dinv[s]) / 3
__global__ void gather2_kernel(const float* __restrict__ xu,
                               const float* __restrict__ xi,
                               const float* __restrict__ T,
                               const int* __restrict__ row_ptr,
                               const int* __restrict__ adj,
                               const float* __restrict__ dinv,
                               int N, int U, float* __restrict__ out) {
    long gt = (long)blockIdx.x * blockDim.x + threadIdx.x;
    int lane = (int)(gt & 63);
    long node = gt >> 6;
    if (node >= N) return;
    int start = row_ptr[node], end = row_ptr[node + 1];
    float2 acc = {0.f, 0.f};
    for (int j = start; j < end; j++) {
        int s = adj[j];
        float w = dinv[s];
        float2 v = *reinterpret_cast<const float2*>(T + (size_t)s * DIM + lane * 2);
        acc.x += v.x * w;
        acc.y += v.y * w;
    }
    float dd = dinv[node];
    size_t off = (size_t)node * DIM + lane * 2;
    float2 t = *reinterpret_cast<const float2*>(T + off);
    const float* x0p = (node < U) ? (xu + off)
                                  : (xi + off - (size_t)U * DIM);
    float2 x0 = *reinterpret_cast<const float2*>(x0p);
    const float k = 1.0f / 3.0f;
    float2 r;
    r.x = (x0.x + t.x + acc.x * dd) * k;
    r.y = (x0.y + t.y + acc.y * dd) * k;
    *reinterpret_cast<float2*>(out + off) = r;
}

extern "C" void kernel_launch(void* const* d_in, const int* in_sizes, int n_in,
                              void* d_out, int out_size, void* d_ws, size_t ws_size,
                              hipStream_t stream) {
    const float* user_emb = (const float*)d_in[0];
    const float* item_emb = (const float*)d_in[1];
    const int* ui_src = (const int*)d_in[2];
    const int* ui_dst = (const int*)d_in[3];
    const int* iu_src = (const int*)d_in[4];
    const int* iu_dst = (const int*)d_in[5];

    const int E = in_sizes[2];
    const int U = in_sizes[0] / DIM;
    const int I = in_sizes[1] / DIM;
    const int N = U + I;
    const int twoE = 2 * E;

    float* out = (float*)d_out;

    // ws layout (4B-typed, keep T 512B-aligned at the end of the small region)
    char* ws = (char*)d_ws;
    size_t off = 0;
    int* deg = (int*)(ws + off); off += (size_t)N * 4;
    int* cursor = (int*)(ws + off); off += (size_t)N * 4;
    int* row_ptr = (int*)(ws + off); off += (size_t)(N + 1) * 4;
    int* partials = (int*)(ws + off); off += 1024 * 4;
    float* dinv = (float*)(ws + off); off += (size_t)N * 4;
    int* adj = (int*)(ws + off); off += (size_t)twoE * 4;
    off = (off + 511) & ~(size_t)511;
    float* T = (float*)(ws + off);

    const int nPartBlocks = (N + 255) / 256;  // 586 for N=150000

    hipMemsetAsync(deg, 0, (size_t)N * 4, stream);

    deg_kernel<<<(E + 255) / 256, 256, 0, stream>>>(ui_dst, iu_dst, E, U, deg);

    scan_partial_kernel<<<nPartBlocks, 256, 0, stream>>>(deg, N, partials);
    scan_top_kernel<<<1, 1024, 0, stream>>>(partials, nPartBlocks, row_ptr, N);
    scan_final_kernel<<<nPartBlocks, 256, 0, stream>>>(deg, N, partials,
                                                       row_ptr, cursor, dinv);

    fill_kernel<<<(E + 255) / 256, 256, 0, stream>>>(ui_src, ui_dst, iu_src, iu_dst,
                                                     E, U, cursor, adj);

    {
        long threads = (long)N * 64;
        int blocks = (int)((threads + 255) / 256);
        gather1_kernel<<<blocks, 256, 0, stream>>>(user_emb, item_emb,
                                                   row_ptr, adj, dinv, N, U, T);
        gather2_kernel<<<blocks, 256, 0, stream>>>(user_emb, item_emb, T,
                                                   row_ptr, adj, dinv, N, U, out);
    }
}

// Round 3
// 320.482 us; speedup vs baseline: 6.7924x; 1.2176x over previous
//
#include <hip/hip_runtime.h>
#include <hip/hip_bf16.h>

// LightGCN forward on MI355X — pull-based CSR gather, 32-lane/node float4,
// edge-weight pairs precomputed to break the dependent load chain.
// Node order: users [0,U), items [U, U+I). D = 128 fixed.
// out = (x0 + A x0 + A A x0) / 3, A = D^-1/2 Adj D^-1/2 (no self loops).

#define DIM 128

struct __align__(8) Pair { int s; float w; };

// ---------------- degree histogram ----------------
__global__ void deg_kernel(const int* __restrict__ ui_dst,
                           const int* __restrict__ iu_dst,
                           int E, int U, int* __restrict__ deg) {
    int e = blockIdx.x * blockDim.x + threadIdx.x;
    if (e < E) {
        atomicAdd(&deg[ui_dst[e] + U], 1);
        atomicAdd(&deg[iu_dst[e]], 1);
    }
}

// ---------------- hierarchical exclusive scan ----------------
__device__ __forceinline__ int block_incl_scan(int v, int* lds) {
    int lane = threadIdx.x & 63;
    int wid = threadIdx.x >> 6;
    int nw = (blockDim.x + 63) >> 6;
    #pragma unroll
    for (int off = 1; off < 64; off <<= 1) {
        int t = __shfl_up(v, off);
        if (lane >= off) v += t;
    }
    if (lane == 63) lds[wid] = v;
    __syncthreads();
    if (threadIdx.x == 0) {
        int s = 0;
        for (int w = 0; w < nw; w++) { int t = lds[w]; lds[w] = s; s += t; }
    }
    __syncthreads();
    return v + lds[wid];
}

__global__ void scan_partial_kernel(const int* __restrict__ deg, int N,
                                    int* __restrict__ partials) {
    __shared__ int lds[16];
    int i = blockIdx.x * 256 + threadIdx.x;
    int v = (i < N) ? deg[i] : 0;
    int incl = block_incl_scan(v, lds);
    if (threadIdx.x == 255) partials[blockIdx.x] = incl;
}

__global__ void scan_top_kernel(int* __restrict__ partials, int P,
                                int* __restrict__ row_ptr, int N) {
    __shared__ int lds[16];
    int i = threadIdx.x;
    int v = (i < P) ? partials[i] : 0;
    int incl = block_incl_scan(v, lds);
    if (i < P) partials[i] = incl - v;                // exclusive
    if (i == (int)blockDim.x - 1) row_ptr[N] = incl;  // grand total
}

__global__ void scan_final_kernel(const int* __restrict__ deg, int N,
                                  const int* __restrict__ partials,
                                  int* __restrict__ row_ptr,
                                  int* __restrict__ cursor,
                                  float* __restrict__ dinv) {
    __shared__ int lds[16];
    int i = blockIdx.x * 256 + threadIdx.x;
    int v = (i < N) ? deg[i] : 0;
    int incl = block_incl_scan(v, lds);
    if (i < N) {
        int excl = incl - v + partials[blockIdx.x];
        row_ptr[i] = excl;
        cursor[i] = excl;
        dinv[i] = (v > 0) ? (1.0f / sqrtf((float)v)) : 0.0f;
    }
}

// ---------------- CSR fill: (src, dinv[src]) pairs by destination ----------------
__global__ void fill_kernel(const int* __restrict__ ui_src,
                            const int* __restrict__ ui_dst,
                            const int* __restrict__ iu_src,
                            const int* __restrict__ iu_dst,
                            const float* __restrict__ dinv,
                            int E, int U,
                            int* __restrict__ cursor, Pair* __restrict__ pairs) {
    int e = blockIdx.x * blockDim.x + threadIdx.x;
    if (e >= E) return;
    int s = ui_src[e], d = ui_dst[e] + U;
    int pos = atomicAdd(&cursor[d], 1);
    pairs[pos] = {s, dinv[s]};
    s = iu_src[e] + U; d = iu_dst[e];
    pos = atomicAdd(&cursor[d], 1);
    pairs[pos] = {s, dinv[s]};
}

// ---------------- gather layer 1 ----------------
// 32 lanes per node (2 nodes/wave), float4 per lane, 2-way unrolled.
__global__ __launch_bounds__(256) void gather1_kernel(
        const float* __restrict__ xu, const float* __restrict__ xi,
        const int* __restrict__ row_ptr, const Pair* __restrict__ pairs,
        const float* __restrict__ dinv, int N, int U, float* __restrict__ T) {
    long gt = (long)blockIdx.x * blockDim.x + threadIdx.x;
    int lane = (int)(gt & 31);
    long node = gt >> 5;
    if (node >= N) return;
    int start = row_ptr[node], end = row_ptr[node + 1];
    float4 acc = {0.f, 0.f, 0.f, 0.f};
    int j = start;
    for (; j + 2 <= end; j += 2) {
        Pair p0 = pairs[j];
        Pair p1 = pairs[j + 1];
        const float* a0 = (p0.s < U) ? xu + (size_t)p0.s * DIM
                                     : xi + (size_t)(p0.s - U) * DIM;
        const float* a1 = (p1.s < U) ? xu + (size_t)p1.s * DIM
                                     : xi + (size_t)(p1.s - U) * DIM;
        float4 v0 = *reinterpret_cast<const float4*>(a0 + lane * 4);
        float4 v1 = *reinterpret_cast<const float4*>(a1 + lane * 4);
        acc.x += v0.x * p0.w + v1.x * p1.w;
        acc.y += v0.y * p0.w + v1.y * p1.w;
        acc.z += v0.z * p0.w + v1.z * p1.w;
        acc.w += v0.w * p0.w + v1.w * p1.w;
    }
    if (j < end) {
        Pair p = pairs[j];
        const float* a = (p.s < U) ? xu + (size_t)p.s * DIM
                                   : xi + (size_t)(p.s - U) * DIM;
        float4 v = *reinterpret_cast<const float4*>(a + lane * 4);
        acc.x += v.x * p.w; acc.y += v.y * p.w;
        acc.z += v.z * p.w; acc.w += v.w * p.w;
    }
    float dd = dinv[node];
    float4 r = {acc.x * dd, acc.y * dd, acc.z * dd, acc.w * dd};
    *reinterpret_cast<float4*>(T + (size_t)node * DIM + lane * 4) = r;
}

// ---------------- gather layer 2 + combine ----------------
// out[d] = (x0[d] + T[d] + dinv[d] * sum_s T[s]*dinv[s]) / 3
__global__ __launch_bounds__(256) void gather2_kernel(
        const float* __restrict__ xu, const float* __restrict__ xi,
        const float* __restrict__ T,
        const int* __restrict__ row_ptr, const Pair* __restrict__ pairs,
        const float* __restrict__ dinv, int N, int U, float* __restrict__ out) {
    long gt = (long)blockIdx.x * blockDim.x + threadIdx.x;
    int lane = (int)(gt & 31);
    long node = gt >> 5;
    if (node >= N) return;
    int start = row_ptr[node], end = row_ptr[node + 1];
    float4 acc = {0.f, 0.f, 0.f, 0.f};
    int j = start;
    for (; j + 2 <= end; j += 2) {
        Pair p0 = pairs[j];
        Pair p1 = pairs[j + 1];
        const float* a0 = T + (size_t)p0.s * DIM;
        const float* a1 = T + (size_t)p1.s * DIM;
        float4 v0 = *reinterpret_cast<const float4*>(a0 + lane * 4);
        float4 v1 = *reinterpret_cast<const float4*>(a1 + lane * 4);
        acc.x += v0.x * p0.w + v1.x * p1.w;
        acc.y += v0.y * p0.w + v1.y * p1.w;
        acc.z += v0.z * p0.w + v1.z * p1.w;
        acc.w += v0.w * p0.w + v1.w * p1.w;
    }
    if (j < end) {
        Pair p = pairs[j];
        const float* a = T + (size_t)p.s * DIM;
        float4 v = *reinterpret_cast<const float4*>(a + lane * 4);
        acc.x += v.x * p.w; acc.y += v.y * p.w;
        acc.z += v.z * p.w; acc.w += v.w * p.w;
    }
    float dd = dinv[node];
    size_t off = (size_t)node * DIM + lane * 4;
    float4 t = *reinterpret_cast<const float4*>(T + off);
    const float* x0p = (node < U) ? (xu + off) : (xi + off - (size_t)U * DIM);
    float4 x0 = *reinterpret_cast<const float4*>(x0p);
    const float k = 1.0f / 3.0f;
    float4 r;
    r.x = (x0.x + t.x + acc.x * dd) * k;
    r.y = (x0.y + t.y + acc.y * dd) * k;
    r.z = (x0.z + t.z + acc.z * dd) * k;
    r.w = (x0.w + t.w + acc.w * dd) * k;
    *reinterpret_cast<float4*>(out + off) = r;
}

extern "C" void kernel_launch(void* const* d_in, const int* in_sizes, int n_in,
                              void* d_out, int out_size, void* d_ws, size_t ws_size,
                              hipStream_t stream) {
    const float* user_emb = (const float*)d_in[0];
    const float* item_emb = (const float*)d_in[1];
    const int* ui_src = (const int*)d_in[2];
    const int* ui_dst = (const int*)d_in[3];
    const int* iu_src = (const int*)d_in[4];
    const int* iu_dst = (const int*)d_in[5];

    const int E = in_sizes[2];
    const int U = in_sizes[0] / DIM;
    const int I = in_sizes[1] / DIM;
    const int N = U + I;
    const int twoE = 2 * E;

    float* out = (float*)d_out;

    // ws layout
    char* ws = (char*)d_ws;
    size_t off = 0;
    int* deg = (int*)(ws + off); off += (size_t)N * 4;
    int* cursor = (int*)(ws + off); off += (size_t)N * 4;
    int* row_ptr = (int*)(ws + off); off += (size_t)(N + 1) * 4;
    int* partials = (int*)(ws + off); off += 1024 * 4;
    float* dinv = (float*)(ws + off); off += (size_t)N * 4;
    off = (off + 7) & ~(size_t)7;
    Pair* pairs = (Pair*)(ws + off); off += (size_t)twoE * 8;
    off = (off + 511) & ~(size_t)511;
    float* T = (float*)(ws + off);

    const int nPartBlocks = (N + 255) / 256;

    hipMemsetAsync(deg, 0, (size_t)N * 4, stream);

    deg_kernel<<<(E + 255) / 256, 256, 0, stream>>>(ui_dst, iu_dst, E, U, deg);

    scan_partial_kernel<<<nPartBlocks, 256, 0, stream>>>(deg, N, partials);
    scan_top_kernel<<<1, 1024, 0, stream>>>(partials, nPartBlocks, row_ptr, N);
    scan_final_kernel<<<nPartBlocks, 256, 0, stream>>>(deg, N, partials,
                                                       row_ptr, cursor, dinv);

    fill_kernel<<<(E + 255) / 256, 256, 0, stream>>>(ui_src, ui_dst, iu_src, iu_dst,
                                                     dinv, E, U, cursor, pairs);

    {
        long threads = (long)N * 32;
        int blocks = (int)((threads + 255) / 256);
        gather1_kernel<<<blocks, 256, 0, stream>>>(user_emb, item_emb,
                                                   row_ptr, pairs, dinv, N, U, T);
        gather2_kernel<<<blocks, 256, 0, stream>>>(user_emb, item_emb, T,
                                                   row_ptr, pairs, dinv, N, U, out);
    }
}

// Round 4
// 292.356 us; speedup vs baseline: 7.4458x; 1.0962x over previous
//
#include <hip/hip_runtime.h>
#include <hip/hip_bf16.h>

// LightGCN forward on MI355X — pull-based CSR gather with bf16 operand tables.
// Node order: users [0,U), items [U, U+I). D = 128 fixed.
// out = (x0 + A x0 + A A x0) / 3, A = D^-1/2 Adj D^-1/2 (no self loops).
// Random-gathered tables (xb = bf16(x0), Tb = bf16(A x0)) are 38.4 MB each ->
// L3-resident; accumulation in fp32; final combine reads x0 in fp32.

#define DIM 128

struct __align__(8) Pair { int s; float w; };

// round-to-nearest-even f32 -> bf16 bits
__device__ __forceinline__ ushort f2bf(float f) {
    uint u = __float_as_uint(f);
    u += 0x7fffu + ((u >> 16) & 1u);
    return (ushort)(u >> 16);
}
__device__ __forceinline__ float bflo(uint u) { return __uint_as_float(u << 16); }
__device__ __forceinline__ float bfhi(uint u) { return __uint_as_float(u & 0xffff0000u); }

// ---------------- degree histogram ----------------
__global__ void deg_kernel(const int* __restrict__ ui_dst,
                           const int* __restrict__ iu_dst,
                           int E, int U, int* __restrict__ deg) {
    int e = blockIdx.x * blockDim.x + threadIdx.x;
    if (e < E) {
        atomicAdd(&deg[ui_dst[e] + U], 1);
        atomicAdd(&deg[iu_dst[e]], 1);
    }
}

// ---------------- hierarchical exclusive scan ----------------
__device__ __forceinline__ int block_incl_scan(int v, int* lds) {
    int lane = threadIdx.x & 63;
    int wid = threadIdx.x >> 6;
    int nw = (blockDim.x + 63) >> 6;
    #pragma unroll
    for (int off = 1; off < 64; off <<= 1) {
        int t = __shfl_up(v, off);
        if (lane >= off) v += t;
    }
    if (lane == 63) lds[wid] = v;
    __syncthreads();
    if (threadIdx.x == 0) {
        int s = 0;
        for (int w = 0; w < nw; w++) { int t = lds[w]; lds[w] = s; s += t; }
    }
    __syncthreads();
    return v + lds[wid];
}

__global__ void scan_partial_kernel(const int* __restrict__ deg, int N,
                                    int* __restrict__ partials) {
    __shared__ int lds[16];
    int i = blockIdx.x * 256 + threadIdx.x;
    int v = (i < N) ? deg[i] : 0;
    int incl = block_incl_scan(v, lds);
    if (threadIdx.x == 255) partials[blockIdx.x] = incl;
}

__global__ void scan_top_kernel(int* __restrict__ partials, int P,
                                int* __restrict__ row_ptr, int N) {
    __shared__ int lds[16];
    int i = threadIdx.x;
    int v = (i < P) ? partials[i] : 0;
    int incl = block_incl_scan(v, lds);
    if (i < P) partials[i] = incl - v;                // exclusive
    if (i == (int)blockDim.x - 1) row_ptr[N] = incl;  // grand total
}

__global__ void scan_final_kernel(const int* __restrict__ deg, int N,
                                  const int* __restrict__ partials,
                                  int* __restrict__ row_ptr,
                                  int* __restrict__ cursor,
                                  float* __restrict__ dinv) {
    __shared__ int lds[16];
    int i = blockIdx.x * 256 + threadIdx.x;
    int v = (i < N) ? deg[i] : 0;
    int incl = block_incl_scan(v, lds);
    if (i < N) {
        int excl = incl - v + partials[blockIdx.x];
        row_ptr[i] = excl;
        cursor[i] = excl;
        dinv[i] = (v > 0) ? (1.0f / sqrtf((float)v)) : 0.0f;
    }
}

// ---------------- CSR fill: (src, dinv[src]) pairs by destination ----------------
__global__ void fill_kernel(const int* __restrict__ ui_src,
                            const int* __restrict__ ui_dst,
                            const int* __restrict__ iu_src,
                            const int* __restrict__ iu_dst,
                            const float* __restrict__ dinv,
                            int E, int U,
                            int* __restrict__ cursor, Pair* __restrict__ pairs) {
    int e = blockIdx.x * blockDim.x + threadIdx.x;
    if (e >= E) return;
    int s = ui_src[e], d = ui_dst[e] + U;
    int pos = atomicAdd(&cursor[d], 1);
    pairs[pos] = {s, dinv[s]};
    s = iu_src[e] + U; d = iu_dst[e];
    pos = atomicAdd(&cursor[d], 1);
    pairs[pos] = {s, dinv[s]};
}

// ---------------- x0 (fp32, split) -> xb (bf16, contiguous) ----------------
__global__ void convert_kernel(const float* __restrict__ xu,
                               const float* __restrict__ xi,
                               long uelems, long total,
                               ushort* __restrict__ xb) {
    long i8 = ((long)blockIdx.x * blockDim.x + threadIdx.x) * 8;
    if (i8 >= total) return;
    const float* src = (i8 < uelems) ? (xu + i8) : (xi + (i8 - uelems));
    float4 a = *reinterpret_cast<const float4*>(src);
    float4 b = *reinterpret_cast<const float4*>(src + 4);
    uint4 q;
    q.x = ((uint)f2bf(a.y) << 16) | f2bf(a.x);
    q.y = ((uint)f2bf(a.w) << 16) | f2bf(a.z);
    q.z = ((uint)f2bf(b.y) << 16) | f2bf(b.x);
    q.w = ((uint)f2bf(b.w) << 16) | f2bf(b.z);
    *reinterpret_cast<uint4*>(xb + i8) = q;
}

// ---------------- gather layer 1: Tb[d] = bf16( dinv[d] * sum_s xb[s]*w ) ----
// 16 lanes per node (4 nodes/wave), 16B (8 bf16) per lane, 2-way unrolled.
__global__ __launch_bounds__(256) void gather1_kernel(
        const ushort* __restrict__ xb,
        const int* __restrict__ row_ptr, const Pair* __restrict__ pairs,
        const float* __restrict__ dinv, int N, ushort* __restrict__ Tb) {
    long gt = (long)blockIdx.x * blockDim.x + threadIdx.x;
    int lane = (int)(gt & 15);
    long node = gt >> 4;
    if (node >= N) return;
    int start = row_ptr[node], end = row_ptr[node + 1];
    float a0 = 0.f, a1 = 0.f, a2 = 0.f, a3 = 0.f, a4 = 0.f, a5 = 0.f, a6 = 0.f, a7 = 0.f;
    int j = start;
    for (; j + 2 <= end; j += 2) {
        Pair p0 = pairs[j], p1 = pairs[j + 1];
        uint4 q0 = *reinterpret_cast<const uint4*>(xb + (size_t)p0.s * DIM + lane * 8);
        uint4 q1 = *reinterpret_cast<const uint4*>(xb + (size_t)p1.s * DIM + lane * 8);
        a0 = fmaf(bflo(q0.x), p0.w, fmaf(bflo(q1.x), p1.w, a0));
        a1 = fmaf(bfhi(q0.x), p0.w, fmaf(bfhi(q1.x), p1.w, a1));
        a2 = fmaf(bflo(q0.y), p0.w, fmaf(bflo(q1.y), p1.w, a2));
        a3 = fmaf(bfhi(q0.y), p0.w, fmaf(bfhi(q1.y), p1.w, a3));
        a4 = fmaf(bflo(q0.z), p0.w, fmaf(bflo(q1.z), p1.w, a4));
        a5 = fmaf(bfhi(q0.z), p0.w, fmaf(bfhi(q1.z), p1.w, a5));
        a6 = fmaf(bflo(q0.w), p0.w, fmaf(bflo(q1.w), p1.w, a6));
        a7 = fmaf(bfhi(q0.w), p0.w, fmaf(bfhi(q1.w), p1.w, a7));
    }
    if (j < end) {
        Pair p = pairs[j];
        uint4 q = *reinterpret_cast<const uint4*>(xb + (size_t)p.s * DIM + lane * 8);
        a0 = fmaf(bflo(q.x), p.w, a0);
        a1 = fmaf(bfhi(q.x), p.w, a1);
        a2 = fmaf(bflo(q.y), p.w, a2);
        a3 = fmaf(bfhi(q.y), p.w, a3);
        a4 = fmaf(bflo(q.z), p.w, a4);
        a5 = fmaf(bfhi(q.z), p.w, a5);
        a6 = fmaf(bflo(q.w), p.w, a6);
        a7 = fmaf(bfhi(q.w), p.w, a7);
    }
    float dd = dinv[node];
    uint4 r;
    r.x = ((uint)f2bf(a1 * dd) << 16) | f2bf(a0 * dd);
    r.y = ((uint)f2bf(a3 * dd) << 16) | f2bf(a2 * dd);
    r.z = ((uint)f2bf(a5 * dd) << 16) | f2bf(a4 * dd);
    r.w = ((uint)f2bf(a7 * dd) << 16) | f2bf(a6 * dd);
    *reinterpret_cast<uint4*>(Tb + (size_t)node * DIM + lane * 8) = r;
}

// ---------------- gather layer 2 + combine (fp32 out) ----------------
// out[d] = (x0[d] + T[d] + dinv[d] * sum_s T[s]*w) / 3
__global__ __launch_bounds__(256) void gather2_kernel(
        const float* __restrict__ xu, const float* __restrict__ xi,
        const ushort* __restrict__ Tb,
        const int* __restrict__ row_ptr, const Pair* __restrict__ pairs,
        const float* __restrict__ dinv, int N, int U, float* __restrict__ out) {
    long gt = (long)blockIdx.x * blockDim.x + threadIdx.x;
    int lane = (int)(gt & 15);
    long node = gt >> 4;
    if (node >= N) return;
    int start = row_ptr[node], end = row_ptr[node + 1];
    float a0 = 0.f, a1 = 0.f, a2 = 0.f, a3 = 0.f, a4 = 0.f, a5 = 0.f, a6 = 0.f, a7 = 0.f;
    int j = start;
    for (; j + 2 <= end; j += 2) {
        Pair p0 = pairs[j], p1 = pairs[j + 1];
        uint4 q0 = *reinterpret_cast<const uint4*>(Tb + (size_t)p0.s * DIM + lane * 8);
        uint4 q1 = *reinterpret_cast<const uint4*>(Tb + (size_t)p1.s * DIM + lane * 8);
        a0 = fmaf(bflo(q0.x), p0.w, fmaf(bflo(q1.x), p1.w, a0));
        a1 = fmaf(bfhi(q0.x), p0.w, fmaf(bfhi(q1.x), p1.w, a1));
        a2 = fmaf(bflo(q0.y), p0.w, fmaf(bflo(q1.y), p1.w, a2));
        a3 = fmaf(bfhi(q0.y), p0.w, fmaf(bfhi(q1.y), p1.w, a3));
        a4 = fmaf(bflo(q0.z), p0.w, fmaf(bflo(q1.z), p1.w, a4));
        a5 = fmaf(bfhi(q0.z), p0.w, fmaf(bfhi(q1.z), p1.w, a5));
        a6 = fmaf(bflo(q0.w), p0.w, fmaf(bflo(q1.w), p1.w, a6));
        a7 = fmaf(bfhi(q0.w), p0.w, fmaf(bfhi(q1.w), p1.w, a7));
    }
    if (j < end) {
        Pair p = pairs[j];
        uint4 q = *reinterpret_cast<const uint4*>(Tb + (size_t)p.s * DIM + lane * 8);
        a0 = fmaf(bflo(q.x), p.w, a0);
        a1 = fmaf(bfhi(q.x), p.w, a1);
        a2 = fmaf(bflo(q.y), p.w, a2);
        a3 = fmaf(bfhi(q.y), p.w, a3);
        a4 = fmaf(bflo(q.z), p.w, a4);
        a5 = fmaf(bfhi(q.z), p.w, a5);
        a6 = fmaf(bflo(q.w), p.w, a6);
        a7 = fmaf(bfhi(q.w), p.w, a7);
    }
    float dd = dinv[node];
    size_t off = (size_t)node * DIM + lane * 8;
    uint4 tq = *reinterpret_cast<const uint4*>(Tb + off);
    const float* x0p = (node < (long)U) ? (xu + off) : (xi + off - (size_t)U * DIM);
    float4 xa = *reinterpret_cast<const float4*>(x0p);
    float4 xc = *reinterpret_cast<const float4*>(x0p + 4);
    const float k = 1.0f / 3.0f;
    float4 r0, r1;
    r0.x = (xa.x + bflo(tq.x) + a0 * dd) * k;
    r0.y = (xa.y + bfhi(tq.x) + a1 * dd) * k;
    r0.z = (xa.z + bflo(tq.y) + a2 * dd) * k;
    r0.w = (xa.w + bfhi(tq.y) + a3 * dd) * k;
    r1.x = (xc.x + bflo(tq.z) + a4 * dd) * k;
    r1.y = (xc.y + bfhi(tq.z) + a5 * dd) * k;
    r1.z = (xc.z + bflo(tq.w) + a6 * dd) * k;
    r1.w = (xc.w + bfhi(tq.w) + a7 * dd) * k;
    *reinterpret_cast<float4*>(out + off) = r0;
    *reinterpret_cast<float4*>(out + off + 4) = r1;
}

extern "C" void kernel_launch(void* const* d_in, const int* in_sizes, int n_in,
                              void* d_out, int out_size, void* d_ws, size_t ws_size,
                              hipStream_t stream) {
    const float* user_emb = (const float*)d_in[0];
    const float* item_emb = (const float*)d_in[1];
    const int* ui_src = (const int*)d_in[2];
    const int* ui_dst = (const int*)d_in[3];
    const int* iu_src = (const int*)d_in[4];
    const int* iu_dst = (const int*)d_in[5];

    const int E = in_sizes[2];
    const int U = in_sizes[0] / DIM;
    const int I = in_sizes[1] / DIM;
    const int N = U + I;
    const int twoE = 2 * E;
    const long uelems = (long)U * DIM;
    const long total = (long)N * DIM;

    float* out = (float*)d_out;

    // ws layout
    char* ws = (char*)d_ws;
    size_t off = 0;
    int* deg = (int*)(ws + off); off += (size_t)N * 4;
    int* cursor = (int*)(ws + off); off += (size_t)N * 4;
    int* row_ptr = (int*)(ws + off); off += (size_t)(N + 1) * 4;
    int* partials = (int*)(ws + off); off += 1024 * 4;
    float* dinv = (float*)(ws + off); off += (size_t)N * 4;
    off = (off + 7) & ~(size_t)7;
    Pair* pairs = (Pair*)(ws + off); off += (size_t)twoE * 8;
    off = (off + 511) & ~(size_t)511;
    ushort* xb = (ushort*)(ws + off); off += (size_t)total * 2;
    off = (off + 511) & ~(size_t)511;
    ushort* Tb = (ushort*)(ws + off);

    const int nPartBlocks = (N + 255) / 256;

    hipMemsetAsync(deg, 0, (size_t)N * 4, stream);

    deg_kernel<<<(E + 255) / 256, 256, 0, stream>>>(ui_dst, iu_dst, E, U, deg);

    scan_partial_kernel<<<nPartBlocks, 256, 0, stream>>>(deg, N, partials);
    scan_top_kernel<<<1, 1024, 0, stream>>>(partials, nPartBlocks, row_ptr, N);
    scan_final_kernel<<<nPartBlocks, 256, 0, stream>>>(deg, N, partials,
                                                       row_ptr, cursor, dinv);

    fill_kernel<<<(E + 255) / 256, 256, 0, stream>>>(ui_src, ui_dst, iu_src, iu_dst,
                                                     dinv, E, U, cursor, pairs);

    {
        long cthreads = total / 8;
        int cblocks = (int)((cthreads + 255) / 256);
        convert_kernel<<<cblocks, 256, 0, stream>>>(user_emb, item_emb,
                                                    uelems, total, xb);
    }

    {
        long threads = (long)N * 16;
        int blocks = (int)((threads + 255) / 256);
        gather1_kernel<<<blocks, 256, 0, stream>>>(xb, row_ptr, pairs, dinv, N, Tb);
        gather2_kernel<<<blocks, 256, 0, stream>>>(user_emb, item_emb, Tb,
                                                   row_ptr, pairs, dinv, N, U, out);
    }
}